// Round 9
// baseline (487.772 us; speedup 1.0000x reference)
//
#include <hip/hip_runtime.h>
#include <hip/hip_bf16.h>
#include <hip/hip_cooperative_groups.h>

namespace cg = cooperative_groups;

#define T_ 64
#define B_ 8
#define H_ 128
#define NH_ 4
#define D_ 256
#define TB_ 512          // T_*B_
#define EPS_ 1e-5f

typedef short bf16x8 __attribute__((ext_vector_type(8)));
typedef float f32x4 __attribute__((ext_vector_type(4)));

__device__ __forceinline__ float silu_(float x){ return x / (1.0f + __expf(-x)); }
__device__ __forceinline__ float sigm_(float x){ return 1.0f / (1.0f + __expf(-x)); }
__device__ __forceinline__ unsigned short tobf_(float f){
  unsigned u = __float_as_uint(f);
  u += 0x7FFF + ((u >> 16) & 1);          // round-to-nearest-even
  return (unsigned short)(u >> 16);
}
// A-fragment-linear address, element (m,k) of [M x 256] bf16 matrix (K=256)
__device__ __forceinline__ int afrag_(int m, int k){
  return (((m >> 4)*8 + (k >> 5))*64 + ((k >> 3)&3)*16 + (m & 15))*8 + (k & 7);
}
// generalized for K=1024 (32 kb per m-tile)
__device__ __forceinline__ int afrag1024_(int m, int k){
  return (((m >> 4)*32 + (k >> 5))*64 + ((k >> 3)&3)*16 + (m & 15))*8 + (k & 7);
}

struct KArgs {
  const float *x, *Wq, *bq, *Wk, *bk, *Wv, *bv, *ck, *cb, *Wi, *bi, *Wf, *bfv;
  const float *Wo, *bo, *Wsk, *bsk, *bn1s, *bn1b, *bn2s, *bn2b;
  const float *Wup1, *bup1, *Wup2, *bup2, *Wp, *bp, *Wd, *bd;
  float *y;
  float *trig, *hbuf, *og, *itb, *ftb;
  unsigned short *xinb, *qkb, *Wqt, *Wkt, *Wst, *Wvt, *Wot, *Wu1t, *Wu2t;
  unsigned short *qob, *kob, *vot, *hob, *Wpt, *Wdt;
};

// One cooperative kernel: 256 blocks x 256 threads, 6 phases, 5 grid syncs.
__global__ __launch_bounds__(256) void k_all(KArgs A){
  cg::grid_group grid = cg::this_grid();
  __shared__ __align__(16) unsigned char smem[32768];
  int bid = blockIdx.x;
  int tid = threadIdx.x;
  int w = tid >> 6, l = tid & 63, lm = l & 15, lq = l >> 4;

  // ================= P1: convert Wu (units 0..31) + Wq/Wk/Ws/Wv/Wo (32..671) =================
  for (int u = bid; u < 672; u += 256){
    if (u < 32){
      const float* Win = (u < 16) ? A.Wup1 : A.Wup2;
      unsigned short* Wout = (u < 16) ? A.Wu1t : A.Wu2t;
      int gid = (u & 15)*256 + tid;
      int combo = gid >> 6;                // nt*4 + kb (K=128)
      int ll = gid & 63;
      int n = (combo >> 2)*16 + (ll & 15);
      int k0 = (combo & 3)*32 + (ll >> 4)*8;
      bf16x8 v;
      #pragma unroll
      for (int j = 0; j < 8; j++) v[j] = (short)tobf_(Win[(k0+j)*D_ + n]);
      *(bf16x8*)(Wout + (combo*64 + ll)*8) = v;
    } else {
      int q = u - 32;
      int sub = q & 31, h = (q >> 5) & 3, mat = q >> 7;
      const float* Win; unsigned short* Wout;
      switch (mat){
        case 0: Win = A.Wq;  Wout = A.Wqt; break;
        case 1: Win = A.Wk;  Wout = A.Wkt; break;
        case 2: Win = A.Wsk; Wout = A.Wst; break;
        case 3: Win = A.Wv;  Wout = A.Wvt; break;
        default: Win = A.Wo; Wout = A.Wot; break;
      }
      Win  += h * (D_*D_);
      Wout += h * (D_*D_);
      int gid = sub*256 + tid;
      int combo = gid >> 6;                // nt*8 + kb
      int ll = gid & 63;
      int n = (combo >> 3)*16 + (ll & 15);
      int k0 = (combo & 7)*32 + (ll >> 4)*8;
      bf16x8 v;
      #pragma unroll
      for (int j = 0; j < 8; j++) v[j] = (short)tobf_(Win[(k0+j)*D_ + n]);
      *(bf16x8*)(Wout + (combo*64 + ll)*8) = v;
    }
  }
  __threadfence();
  grid.sync();

  // ================= P2: blocks 0..63 = bn1+up GEMM+conv+gates; 64..207 = Wp/Wd convert ======
  if (bid < 64){
    float* xs = (float*)smem;                              // [16][257]
    unsigned short* uf = (unsigned short*)(smem + 16448);  // 16x128 A-frag
    int mat = bid >> 5, rt = bid & 31;
    {
      int tl = tid >> 7, hf = tid & 127;
      int t = rt*2 + tl;
      const float* xp = A.x + t*(B_*H_) + hf;
      float v0[8]; float mu = 0.f;
      #pragma unroll
      for (int b = 0; b < 8; b++){ v0[b] = xp[b*H_]; mu += v0[b]; }
      mu *= 0.125f;
      float var = 0.f;
      #pragma unroll
      for (int b = 0; b < 8; b++){ float dd = v0[b]-mu; var += dd*dd; }
      var *= 0.125f;
      float sc = (1.0f/sqrtf(var + EPS_)) * A.bn1s[hf];
      float bs = A.bn1b[hf];
      int base = ((hf >> 5)*64 + ((hf >> 3)&3)*16)*8 + (hf & 7);
      #pragma unroll
      for (int b = 0; b < 8; b++){
        int m = tl*8 + b;
        uf[base + m*8] = tobf_((v0[b]-mu)*sc + bs);
      }
    }
    __syncthreads();
    const unsigned short* Bt = (mat == 0) ? A.Wu1t : A.Wu2t;
    f32x4 acc[4];
    #pragma unroll
    for (int nt = 0; nt < 4; nt++) acc[nt] = (f32x4){0.f,0.f,0.f,0.f};
    const unsigned short* Bp = Bt + l*8;
    #pragma unroll
    for (int kb = 0; kb < 4; kb++){
      bf16x8 a = *(const bf16x8*)(uf + (kb*64 + l)*8);
      #pragma unroll
      for (int nt = 0; nt < 4; nt++){
        bf16x8 bfr = *(const bf16x8*)(Bp + (((w*4+nt)*4 + kb) << 9));
        acc[nt] = __builtin_amdgcn_mfma_f32_16x16x32_bf16(a, bfr, acc[nt], 0, 0, 0);
      }
    }
    const float* bias = (mat == 0) ? A.bup1 : A.bup2;
    #pragma unroll
    for (int nt = 0; nt < 4; nt++){
      #pragma unroll
      for (int r = 0; r < 4; r++){
        int m = lq*4 + r;
        int row = rt*16 + m;
        int e = w*64 + nt*16 + lm;
        float vv = acc[nt][r] + bias[e];
        if (mat == 1){
          A.trig[row*D_ + e] = silu_(vv);
        } else {
          A.xinb[afrag_(row, e)] = tobf_(vv);
          xs[m*257 + e] = vv;
        }
      }
    }
    if (mat == 0){
      __syncthreads();
      int d = tid;
      #pragma unroll 4
      for (int m = 0; m < 16; m++){
        float x0  = xs[m*257 + d];
        float xm1 = (d >= 1)   ? xs[m*257 + d-1] : 0.f;
        float xp1 = (d <= 254) ? xs[m*257 + d+1] : 0.f;
        float xp2 = (d <= 253) ? xs[m*257 + d+2] : 0.f;
        int rowg = rt*16 + m;
        int fa = afrag_(rowg, d);
        #pragma unroll
        for (int h = 0; h < NH_; h++){
          float a2 = A.cb[h];
          a2 = fmaf(xm1, A.ck[0*NH_+h], a2);
          a2 = fmaf(x0,  A.ck[1*NH_+h], a2);
          a2 = fmaf(xp1, A.ck[2*NH_+h], a2);
          a2 = fmaf(xp2, A.ck[3*NH_+h], a2);
          A.qkb[h*(TB_*D_) + fa] = tobf_(silu_(a2));
        }
      }
      int dot = tid >> 2, l4 = tid & 3;
      int h = dot >> 4, m = dot & 15;
      float ai = 0.f, af = 0.f;
      const float* wi = A.Wi + h*D_;
      const float* wf = A.Wf + h*D_;
      #pragma unroll 8
      for (int jj = 0; jj < 64; jj++){
        int k = l4*64 + jj;
        float xv = xs[m*257 + k];
        ai = fmaf(xv, wi[k], ai);
        af = fmaf(xv, wf[k], af);
      }
      ai += __shfl_down(ai, 1); af += __shfl_down(af, 1);
      ai += __shfl_down(ai, 2); af += __shfl_down(af, 2);
      if (l4 == 0){
        int rowg = rt*16 + m;
        int t = rowg >> 3, b = rowg & 7;
        A.itb[(h*B_ + b)*T_ + t] = ai + A.bi[h];
        A.ftb[(h*B_ + b)*T_ + t] = af + A.bfv[h];
      }
    }
  } else if (bid < 208){
    int v2 = bid - 64;
    if (v2 < 128){
      // Wpoll [1024 x 256] -> B-frag K=1024
      int gid = v2*256 + tid;
      int combo = gid >> 6;                // nt*32 + kb
      int ll = gid & 63;
      int n = (combo >> 5)*16 + (ll & 15);
      int k0 = (combo & 31)*32 + (ll >> 4)*8;
      bf16x8 v;
      #pragma unroll
      for (int j = 0; j < 8; j++) v[j] = (short)tobf_(A.Wp[(k0+j)*D_ + n]);
      *(bf16x8*)(A.Wpt + (combo*64 + ll)*8) = v;
    } else {
      // Wdown [256 x 128] -> B-frag K=256
      int gid = (v2-128)*256 + tid;
      int combo = gid >> 6;                // nt*8 + kb
      int ll = gid & 63;
      int n = (combo >> 3)*16 + (ll & 15);
      int k0 = (combo & 7)*32 + (ll >> 4)*8;
      bf16x8 v;
      #pragma unroll
      for (int j = 0; j < 8; j++) v[j] = (short)tobf_(A.Wd[(k0+j)*H_ + n]);
      *(bf16x8*)(A.Wdt + (combo*64 + ll)*8) = v;
    }
  }
  __threadfence();
  grid.sync();

  // ================= P3: 5-matmul per-head GEMM (320 units) =================
  for (int u = bid; u < 320; u += 256){
    int rt  = u & 15;
    int h   = (u >> 4) & 3;
    int mat = u >> 6;                    // 0=q 1=k 2=skip 3=v 4=og
    int r0 = rt * 32;
    const unsigned short* Aop = (mat < 3) ? (A.qkb + h*(TB_*D_)) : A.xinb;
    const unsigned short* Bt;
    const float* bias;
    switch (mat){
      case 0: Bt = A.Wqt; bias = A.bq;  break;
      case 1: Bt = A.Wkt; bias = A.bk;  break;
      case 2: Bt = A.Wst; bias = A.bsk; break;
      case 3: Bt = A.Wvt; bias = A.bv;  break;
      default: Bt = A.Wot; bias = A.bo; break;
    }
    Bt += h*(D_*D_);
    f32x4 acc[2][4];
    #pragma unroll
    for (int mt = 0; mt < 2; mt++)
      #pragma unroll
      for (int nt = 0; nt < 4; nt++) acc[mt][nt] = (f32x4){0.f,0.f,0.f,0.f};
    const unsigned short* Ap = Aop + l*8;
    const unsigned short* Bp = Bt + l*8;
    #pragma unroll
    for (int kc = 0; kc < 8; kc++){
      bf16x8 a0 = *(const bf16x8*)(Ap + ((rt*16      + kc) << 9));
      bf16x8 a1 = *(const bf16x8*)(Ap + ((rt*16 + 8  + kc) << 9));
      bf16x8 b0 = *(const bf16x8*)(Bp + (((w*4+0)*8 + kc) << 9));
      bf16x8 b1 = *(const bf16x8*)(Bp + (((w*4+1)*8 + kc) << 9));
      bf16x8 b2 = *(const bf16x8*)(Bp + (((w*4+2)*8 + kc) << 9));
      bf16x8 b3 = *(const bf16x8*)(Bp + (((w*4+3)*8 + kc) << 9));
      acc[0][0] = __builtin_amdgcn_mfma_f32_16x16x32_bf16(a0, b0, acc[0][0], 0, 0, 0);
      acc[0][1] = __builtin_amdgcn_mfma_f32_16x16x32_bf16(a0, b1, acc[0][1], 0, 0, 0);
      acc[0][2] = __builtin_amdgcn_mfma_f32_16x16x32_bf16(a0, b2, acc[0][2], 0, 0, 0);
      acc[0][3] = __builtin_amdgcn_mfma_f32_16x16x32_bf16(a0, b3, acc[0][3], 0, 0, 0);
      acc[1][0] = __builtin_amdgcn_mfma_f32_16x16x32_bf16(a1, b0, acc[1][0], 0, 0, 0);
      acc[1][1] = __builtin_amdgcn_mfma_f32_16x16x32_bf16(a1, b1, acc[1][1], 0, 0, 0);
      acc[1][2] = __builtin_amdgcn_mfma_f32_16x16x32_bf16(a1, b2, acc[1][2], 0, 0, 0);
      acc[1][3] = __builtin_amdgcn_mfma_f32_16x16x32_bf16(a1, b3, acc[1][3], 0, 0, 0);
    }
    float bval[4];
    #pragma unroll
    for (int nt = 0; nt < 4; nt++) bval[nt] = bias[h*D_ + w*64 + nt*16 + lm];
    #pragma unroll
    for (int mt = 0; mt < 2; mt++){
      #pragma unroll
      for (int r = 0; r < 4; r++){
        int row = r0 + mt*16 + lq*4 + r;
        int t = row >> 3, b = row & 7;
        #pragma unroll
        for (int nt = 0; nt < 4; nt++){
          int e = w*64 + nt*16 + lm;
          float vv = acc[mt][nt][r] + bval[nt];
          if (mat <= 1){
            if (mat == 1) vv *= 0.0625f;
            unsigned short* ob = (mat == 0) ? A.qob : A.kob;
            int mt2 = t >> 4, kb2 = e >> 5;
            int lane2 = ((e >> 3)&3)*16 + (t & 15);
            ob[(h*B_ + b)*16384 + ((mt2*8 + kb2)*64 + lane2)*8 + (e & 7)] = tobf_(vv);
          } else if (mat == 3){
            int nt3 = e >> 4, kb3 = t >> 5;
            int lane3 = ((t >> 3)&3)*16 + lm;
            A.vot[(h*B_ + b)*16384 + ((nt3*2 + kb3)*64 + lane3)*8 + (t & 7)] = tobf_(vv);
          } else {
            int obase = (((t*NH_ + h)*B_ + b) << 8) + e;
            if (mat == 4) A.og[obase] = sigm_(vv);
            else          A.hbuf[obase] = vv;      // skip term
          }
        }
      }
    }
  }
  __threadfence();
  grid.sync();

  // ================= P4: MFMA attention + fused gate scan (128 units) =================
  if (bid < 128){
    unsigned short* Pf = (unsigned short*)smem;        // 2 KB
    float* partial = (float*)(smem + 2048);            // [4][16]
    float* scal = (float*)(smem + 2304);               // [16]
    int hbx = bid >> 2, tq = bid & 3;
    int h = hbx >> 3, b = hbx & 7;
    float F  = A.ftb[hbx*T_ + l];
    float it = A.itb[hbx*T_ + l];
    #pragma unroll
    for (int off = 1; off < 64; off <<= 1){
      float v2 = __shfl_up(F, off);
      if (l >= off) F += v2;
    }
    float ct = it - F;
    float G = ct;
    #pragma unroll
    for (int off = 1; off < 64; off <<= 1){
      float v2 = __shfl_up(G, off);
      if (l >= off) G = fmaxf(G, v2);
    }
    float rb = -fmaxf(0.f, G);
    const unsigned short* Aq = A.qob + hbx*16384 + l*8;
    const unsigned short* Bk = A.kob + hbx*16384 + l*8;
    f32x4 accs = (f32x4){0.f,0.f,0.f,0.f};
    #pragma unroll
    for (int kc = 0; kc < 8; kc++){
      bf16x8 a  = *(const bf16x8*)(Aq + ((tq*8 + kc) << 9));
      bf16x8 bb = *(const bf16x8*)(Bk + ((w*8  + kc) << 9));
      accs = __builtin_amdgcn_mfma_f32_16x16x32_bf16(a, bb, accs, 0, 0, 0);
    }
    int s = w*16 + lm;
    float ct_s = __shfl(ct, s);
    float p[4], ps[4];
    #pragma unroll
    for (int r = 0; r < 4; r++){
      int t = tq*16 + lq*4 + r;
      float rb_t = __shfl(rb, t);
      float pv = (s <= t) ? __expf(ct_s + rb_t) * accs[r] : 0.f;
      p[r] = pv; ps[r] = pv;
    }
    #pragma unroll
    for (int off = 1; off < 16; off <<= 1){
      #pragma unroll
      for (int r = 0; r < 4; r++) ps[r] += __shfl_xor(ps[r], off);
    }
    if (lm == 0){
      #pragma unroll
      for (int r = 0; r < 4; r++) partial[w*16 + lq*4 + r] = ps[r];
    }
    {
      int kbP = w >> 1;
      int laneP = ((w*2 + (lm >> 3)) & 3)*16;
      int jP = lm & 7;
      #pragma unroll
      for (int r = 0; r < 4; r++){
        int m = lq*4 + r;
        Pf[(kbP*64 + laneP + m)*8 + jP] = tobf_(p[r]);
      }
    }
    __syncthreads();
    if (tid < 16){
      float sum = partial[0*16+tid] + partial[1*16+tid] + partial[2*16+tid] + partial[3*16+tid];
      scal[tid] = 1.0f / fmaxf(fabsf(sum), 1.0f);
    }
    bf16x8 pa0 = *(const bf16x8*)(Pf + l*8);
    bf16x8 pa1 = *(const bf16x8*)(Pf + 512 + l*8);
    const unsigned short* Bv = A.vot + hbx*16384 + l*8;
    f32x4 acco[4];
    #pragma unroll
    for (int nt = 0; nt < 4; nt++) acco[nt] = (f32x4){0.f,0.f,0.f,0.f};
    #pragma unroll
    for (int nt = 0; nt < 4; nt++){
      int nt3 = w*4 + nt;
      bf16x8 b0 = *(const bf16x8*)(Bv + ((nt3*2 + 0) << 9));
      bf16x8 b1 = *(const bf16x8*)(Bv + ((nt3*2 + 1) << 9));
      acco[nt] = __builtin_amdgcn_mfma_f32_16x16x32_bf16(pa0, b0, acco[nt], 0, 0, 0);
      acco[nt] = __builtin_amdgcn_mfma_f32_16x16x32_bf16(pa1, b1, acco[nt], 0, 0, 0);
    }
    __syncthreads();
    #pragma unroll
    for (int nt = 0; nt < 4; nt++){
      #pragma unroll
      for (int r = 0; r < 4; r++){
        int tl = lq*4 + r;
        int t = tq*16 + tl;
        int e = (w*4 + nt)*16 + lm;
        int idx = (((t*NH_ + h)*B_ + b) << 8) + e;
        A.hbuf[idx] += A.og[idx] * acco[nt][r] * scal[tl];
      }
    }
  }
  __threadfence();
  grid.sync();

  // ================= P5: bn2 -> hob (64 units) =================
  if (bid < 64){
    float* hs = (float*)smem;                  // 32 KB
    int t = bid;
    const float* hp = A.hbuf + (t*NH_*B_)*D_;
    #pragma unroll
    for (int i = 0; i < 8; i++){
      int idx = (tid + i*256)*4;
      *(float4*)&hs[idx] = *(const float4*)&hp[idx];
    }
    __syncthreads();
    int d = tid;
    float v[32]; float mu = 0.f;
    #pragma unroll
    for (int i = 0; i < 32; i++){ v[i] = hs[i*D_ + d]; mu += v[i]; }
    mu *= (1.0f/32.0f);
    float var = 0.f;
    #pragma unroll
    for (int i = 0; i < 32; i++){ float dd = v[i]-mu; var += dd*dd; }
    var *= (1.0f/32.0f);
    float sc = (1.0f/sqrtf(var + EPS_)) * A.bn2s[d];
    float bs = A.bn2b[d];
    #pragma unroll
    for (int i = 0; i < 32; i++){              // i = h*8 + b
      int hh = i >> 3, b = i & 7;
      int m = t*B_ + b;
      int k = hh*D_ + d;
      A.hob[afrag1024_(m, k)] = tobf_((v[i]-mu)*sc + bs);
    }
  }
  __threadfence();
  grid.sync();

  // ================= P6: poll (K=1024, *trig) + down (K=256, +x) — 16 units =================
  if (bid < 16){
    unsigned short* zf = (unsigned short*)smem;    // 16 KB: z A-frag (32 x 256)
    int rt = bid;
    f32x4 acc[2][4];
    #pragma unroll
    for (int mt = 0; mt < 2; mt++)
      #pragma unroll
      for (int nt = 0; nt < 4; nt++) acc[mt][nt] = (f32x4){0.f,0.f,0.f,0.f};
    const unsigned short* Ap = A.hob + l*8;
    const unsigned short* Bp = A.Wpt + l*8;
    #pragma unroll 4
    for (int kc = 0; kc < 32; kc++){
      bf16x8 a0 = *(const bf16x8*)(Ap + (((rt*2+0)*32 + kc) << 9));
      bf16x8 a1 = *(const bf16x8*)(Ap + (((rt*2+1)*32 + kc) << 9));
      #pragma unroll
      for (int nt = 0; nt < 4; nt++){
        bf16x8 bb = *(const bf16x8*)(Bp + (((w*4+nt)*32 + kc) << 9));
        acc[0][nt] = __builtin_amdgcn_mfma_f32_16x16x32_bf16(a0, bb, acc[0][nt], 0, 0, 0);
        acc[1][nt] = __builtin_amdgcn_mfma_f32_16x16x32_bf16(a1, bb, acc[1][nt], 0, 0, 0);
      }
    }
    #pragma unroll
    for (int mt = 0; mt < 2; mt++){
      #pragma unroll
      for (int nt = 0; nt < 4; nt++){
        int e = w*64 + nt*16 + lm;
        float bpe = A.bp[e];
        #pragma unroll
        for (int r = 0; r < 4; r++){
          int ml = mt*16 + lq*4 + r;
          int row = rt*32 + ml;
          float z = (acc[mt][nt][r] + bpe) * A.trig[row*D_ + e];
          zf[afrag_(ml, e)] = tobf_(z);
        }
      }
    }
    __syncthreads();
    f32x4 acc2[2][2];
    #pragma unroll
    for (int mt = 0; mt < 2; mt++)
      #pragma unroll
      for (int nt = 0; nt < 2; nt++) acc2[mt][nt] = (f32x4){0.f,0.f,0.f,0.f};
    const unsigned short* Bdp = A.Wdt + l*8;
    #pragma unroll
    for (int kc = 0; kc < 8; kc++){
      bf16x8 a0 = *(const bf16x8*)(zf + ((0*8 + kc) << 9) + l*8);
      bf16x8 a1 = *(const bf16x8*)(zf + ((1*8 + kc) << 9) + l*8);
      #pragma unroll
      for (int nt = 0; nt < 2; nt++){
        bf16x8 bb = *(const bf16x8*)(Bdp + (((w*2+nt)*8 + kc) << 9));
        acc2[0][nt] = __builtin_amdgcn_mfma_f32_16x16x32_bf16(a0, bb, acc2[0][nt], 0, 0, 0);
        acc2[1][nt] = __builtin_amdgcn_mfma_f32_16x16x32_bf16(a1, bb, acc2[1][nt], 0, 0, 0);
      }
    }
    #pragma unroll
    for (int mt = 0; mt < 2; mt++){
      #pragma unroll
      for (int nt = 0; nt < 2; nt++){
        int hh = w*32 + nt*16 + lm;
        float bde = A.bd[hh];
        #pragma unroll
        for (int r = 0; r < 4; r++){
          int row = rt*32 + mt*16 + lq*4 + r;
          A.y[row*H_ + hh] = acc2[mt][nt][r] + bde + A.x[row*H_ + hh];
        }
      }
    }
  }
}

extern "C" void kernel_launch(void* const* d_in, const int* in_sizes, int n_in,
                              void* d_out, int out_size, void* d_ws, size_t ws_size,
                              hipStream_t stream){
  KArgs A;
  A.x    = (const float*)d_in[0];
  A.Wq   = (const float*)d_in[1];
  A.bq   = (const float*)d_in[2];
  A.Wk   = (const float*)d_in[3];
  A.bk   = (const float*)d_in[4];
  A.Wv   = (const float*)d_in[5];
  A.bv   = (const float*)d_in[6];
  A.ck   = (const float*)d_in[7];
  A.cb   = (const float*)d_in[8];
  A.Wi   = (const float*)d_in[9];
  A.bi   = (const float*)d_in[10];
  A.Wf   = (const float*)d_in[11];
  A.bfv  = (const float*)d_in[12];
  A.Wo   = (const float*)d_in[13];
  A.bo   = (const float*)d_in[14];
  A.Wsk  = (const float*)d_in[15];
  A.bsk  = (const float*)d_in[16];
  A.bn1s = (const float*)d_in[17];
  A.bn1b = (const float*)d_in[18];
  A.bn2s = (const float*)d_in[19];
  A.bn2b = (const float*)d_in[20];
  A.Wup1 = (const float*)d_in[21];
  A.bup1 = (const float*)d_in[22];
  A.Wup2 = (const float*)d_in[23];
  A.bup2 = (const float*)d_in[24];
  A.Wp   = (const float*)d_in[25];
  A.bp   = (const float*)d_in[26];
  A.Wd   = (const float*)d_in[27];
  A.bd   = (const float*)d_in[28];
  A.y    = (float*)d_out;

  float* w = (float*)d_ws;
  A.trig = w;  w += T_*B_*D_;
  A.hbuf = w;  w += T_*NH_*B_*D_;
  A.og   = w;  w += T_*NH_*B_*D_;
  A.itb  = w;  w += NH_*B_*T_;
  A.ftb  = w;  w += NH_*B_*T_;
  A.xinb = (unsigned short*)w;  w += (T_*B_*D_)/2;
  A.qkb  = (unsigned short*)w;  w += (NH_*TB_*D_)/2;
  A.Wqt  = (unsigned short*)w;  w += (NH_*D_*D_)/2;
  A.Wkt  = (unsigned short*)w;  w += (NH_*D_*D_)/2;
  A.Wst  = (unsigned short*)w;  w += (NH_*D_*D_)/2;
  A.Wvt  = (unsigned short*)w;  w += (NH_*D_*D_)/2;
  A.Wot  = (unsigned short*)w;  w += (NH_*D_*D_)/2;
  A.Wu1t = (unsigned short*)w;  w += (H_*D_)/2;
  A.Wu2t = (unsigned short*)w;  w += (H_*D_)/2;
  A.qob  = (unsigned short*)w;  w += (NH_*B_*T_*D_)/2;
  A.kob  = (unsigned short*)w;  w += (NH_*B_*T_*D_)/2;
  A.vot  = (unsigned short*)w;  w += (NH_*B_*T_*D_)/2;
  A.hob  = (unsigned short*)w;  w += (TB_*NH_*D_)/2;
  A.Wpt  = (unsigned short*)w;  w += (NH_*D_*D_)/2;
  A.Wdt  = (unsigned short*)w;  w += (D_*H_)/2;

  void* kparams[] = { (void*)&A };
  hipLaunchCooperativeKernel((const void*)k_all, dim3(256), dim3(256),
                             kparams, 0, stream);
}

// Round 10
// 159.858 us; speedup vs baseline: 3.0513x; 3.0513x over previous
//
#include <hip/hip_runtime.h>
#include <hip/hip_bf16.h>

#define T_ 64
#define B_ 8
#define H_ 128
#define NH_ 4
#define D_ 256
#define TB_ 512          // T_*B_
#define EPS_ 1e-5f

typedef short bf16x8 __attribute__((ext_vector_type(8)));
typedef float f32x4 __attribute__((ext_vector_type(4)));

__device__ __forceinline__ float silu_(float x){ return x / (1.0f + __expf(-x)); }
__device__ __forceinline__ float sigm_(float x){ return 1.0f / (1.0f + __expf(-x)); }
__device__ __forceinline__ unsigned short tobf_(float f){
  unsigned u = __float_as_uint(f);
  u += 0x7FFF + ((u >> 16) & 1);          // round-to-nearest-even
  return (unsigned short)(u >> 16);
}
// A-fragment-linear address, element (m,k) of [M x 256] bf16 matrix (K=256)
__device__ __forceinline__ int afrag_(int m, int k){
  return (((m >> 4)*8 + (k >> 5))*64 + ((k >> 3)&3)*16 + (m & 15))*8 + (k & 7);
}

// ---------------- K1: weight conversions only ----------------
// 0..639: Wq/Wk/Ws/Wv/Wo B-frag | 640..671: Wup1/2 B-frag K=128
// 672..799: Wpoll B-frag K=1024 | 800..815: Wdown B-frag K=256
__global__ __launch_bounds__(256) void k_prep(
    const float* __restrict__ Wq, const float* __restrict__ Wk, const float* __restrict__ Ws,
    const float* __restrict__ Wv, const float* __restrict__ Wo,
    const float* __restrict__ Wup1, const float* __restrict__ Wup2,
    const float* __restrict__ Wp, const float* __restrict__ Wd,
    unsigned short* __restrict__ Wqt, unsigned short* __restrict__ Wkt,
    unsigned short* __restrict__ Wst, unsigned short* __restrict__ Wvt,
    unsigned short* __restrict__ Wot,
    unsigned short* __restrict__ Wu1t, unsigned short* __restrict__ Wu2t,
    unsigned short* __restrict__ Wpt, unsigned short* __restrict__ Wdt){
  int bid = blockIdx.x;
  int tid = threadIdx.x;
  if (bid < 640){
    int sub = bid & 31;
    int h   = (bid >> 5) & 3;
    int mat = bid >> 7;
    const float* Win; unsigned short* Wout;
    switch (mat){
      case 0: Win = Wq; Wout = Wqt; break;
      case 1: Win = Wk; Wout = Wkt; break;
      case 2: Win = Ws; Wout = Wst; break;
      case 3: Win = Wv; Wout = Wvt; break;
      default: Win = Wo; Wout = Wot; break;
    }
    Win  += h * (D_*D_);
    Wout += h * (D_*D_);
    int gid = sub*256 + tid;
    int combo = gid >> 6;                // nt*8 + kb
    int l = gid & 63;
    int n = (combo >> 3)*16 + (l & 15);
    int k0 = (combo & 7)*32 + (l >> 4)*8;
    bf16x8 v;
    #pragma unroll
    for (int j = 0; j < 8; j++) v[j] = (short)tobf_(Win[(k0+j)*D_ + n]);
    *(bf16x8*)(Wout + (combo*64 + l)*8) = v;
  } else if (bid < 672){
    int idx = bid - 640;
    const float* Win = (idx < 16) ? Wup1 : Wup2;
    unsigned short* Wout = (idx < 16) ? Wu1t : Wu2t;
    int sub = idx & 15;
    int gid = sub*256 + tid;             // [0,4096)
    int combo = gid >> 6;                // nt*4 + kb  (K=128)
    int l = gid & 63;
    int n = (combo >> 2)*16 + (l & 15);
    int k0 = (combo & 3)*32 + (l >> 4)*8;
    bf16x8 v;
    #pragma unroll
    for (int j = 0; j < 8; j++) v[j] = (short)tobf_(Win[(k0+j)*D_ + n]);
    *(bf16x8*)(Wout + (combo*64 + l)*8) = v;
  } else if (bid < 800){
    // Wpoll [1024 x 256] -> B-frag K=1024
    int gid = (bid - 672)*256 + tid;     // [0, 32768)
    int combo = gid >> 6;                // nt*32 + kb
    int l = gid & 63;
    int n = (combo >> 5)*16 + (l & 15);
    int k0 = (combo & 31)*32 + (l >> 4)*8;
    bf16x8 v;
    #pragma unroll
    for (int j = 0; j < 8; j++) v[j] = (short)tobf_(Wp[(k0+j)*D_ + n]);
    *(bf16x8*)(Wpt + (combo*64 + l)*8) = v;
  } else {
    // Wdown [256 x 128] -> B-frag K=256
    int gid = (bid - 800)*256 + tid;     // [0, 4096)
    int combo = gid >> 6;                // nt*8 + kb
    int l = gid & 63;
    int n = (combo >> 3)*16 + (l & 15);
    int k0 = (combo & 7)*32 + (l >> 4)*8;
    bf16x8 v;
    #pragma unroll
    for (int j = 0; j < 8; j++) v[j] = (short)tobf_(Wd[(k0+j)*H_ + n]);
    *(bf16x8*)(Wdt + (combo*64 + l)*8) = v;
  }
}

// ---------------- K2: bn1 (fused) + up-proj MFMA + conv/gates (mat0) / trig (mat1) ----------------
// grid 64: mat = bid>>5, rt = bid&31 (16 rows = 2 t)
__global__ __launch_bounds__(256) void k_upcg(
    const float* __restrict__ x, const float* __restrict__ bn1s, const float* __restrict__ bn1b,
    const unsigned short* __restrict__ Wu1t, const unsigned short* __restrict__ Wu2t,
    const float* __restrict__ bup1, const float* __restrict__ bup2,
    const float* __restrict__ ck, const float* __restrict__ cb,
    const float* __restrict__ Wi, const float* __restrict__ bi,
    const float* __restrict__ Wf, const float* __restrict__ bfv,
    unsigned short* __restrict__ xinb, unsigned short* __restrict__ qkb,
    float* __restrict__ trig, float* __restrict__ itb, float* __restrict__ ftb){
  __shared__ float xs[16][257];
  __shared__ unsigned short uf[2048];     // u bf16 A-frag (16 x 128), 4 KB
  int bid = blockIdx.x;
  int mat = bid >> 5, rt = bid & 31;
  int tid = threadIdx.x;
  int w = tid >> 6, l = tid & 63, lm = l & 15, lq = l >> 4;
  {
    int tl = tid >> 7, hf = tid & 127;
    int t = rt*2 + tl;
    const float* xp = x + t*(B_*H_) + hf;
    float v0[8]; float mu = 0.f;
    #pragma unroll
    for (int b = 0; b < 8; b++){ v0[b] = xp[b*H_]; mu += v0[b]; }
    mu *= 0.125f;
    float var = 0.f;
    #pragma unroll
    for (int b = 0; b < 8; b++){ float dd = v0[b]-mu; var += dd*dd; }
    var *= 0.125f;
    float sc = (1.0f/sqrtf(var + EPS_)) * bn1s[hf];
    float bs = bn1b[hf];
    int base = ((hf >> 5)*64 + ((hf >> 3)&3)*16)*8 + (hf & 7);
    #pragma unroll
    for (int b = 0; b < 8; b++){
      int m = tl*8 + b;
      uf[base + m*8] = tobf_((v0[b]-mu)*sc + bs);
    }
  }
  __syncthreads();
  const unsigned short* Bt = (mat == 0) ? Wu1t : Wu2t;
  f32x4 acc[4];
  #pragma unroll
  for (int nt = 0; nt < 4; nt++) acc[nt] = (f32x4){0.f,0.f,0.f,0.f};
  const unsigned short* Bp = Bt + l*8;
  #pragma unroll
  for (int kb = 0; kb < 4; kb++){
    bf16x8 a = *(const bf16x8*)(uf + (kb*64 + l)*8);
    #pragma unroll
    for (int nt = 0; nt < 4; nt++){
      bf16x8 bfr = *(const bf16x8*)(Bp + (((w*4+nt)*4 + kb) << 9));
      acc[nt] = __builtin_amdgcn_mfma_f32_16x16x32_bf16(a, bfr, acc[nt], 0, 0, 0);
    }
  }
  const float* bias = (mat == 0) ? bup1 : bup2;
  #pragma unroll
  for (int nt = 0; nt < 4; nt++){
    #pragma unroll
    for (int r = 0; r < 4; r++){
      int m = lq*4 + r;
      int row = rt*16 + m;
      int e = w*64 + nt*16 + lm;
      float vv = acc[nt][r] + bias[e];
      if (mat == 1){
        trig[row*D_ + e] = silu_(vv);
      } else {
        xinb[afrag_(row, e)] = tobf_(vv);
        xs[m][e] = vv;
      }
    }
  }
  if (mat == 0){
    __syncthreads();
    int d = tid;
    #pragma unroll 4
    for (int m = 0; m < 16; m++){
      float x0  = xs[m][d];
      float xm1 = (d >= 1)   ? xs[m][d-1] : 0.f;
      float xp1 = (d <= 254) ? xs[m][d+1] : 0.f;
      float xp2 = (d <= 253) ? xs[m][d+2] : 0.f;
      int rowg = rt*16 + m;
      int fa = afrag_(rowg, d);
      #pragma unroll
      for (int h = 0; h < NH_; h++){
        float a2 = cb[h];
        a2 = fmaf(xm1, ck[0*NH_+h], a2);
        a2 = fmaf(x0,  ck[1*NH_+h], a2);
        a2 = fmaf(xp1, ck[2*NH_+h], a2);
        a2 = fmaf(xp2, ck[3*NH_+h], a2);
        qkb[h*(TB_*D_) + fa] = tobf_(silu_(a2));
      }
    }
    int dot = tid >> 2, l4 = tid & 3;
    int h = dot >> 4, m = dot & 15;
    float ai = 0.f, af = 0.f;
    const float* wi = Wi + h*D_;
    const float* wf = Wf + h*D_;
    #pragma unroll 8
    for (int jj = 0; jj < 64; jj++){
      int k = l4*64 + jj;
      float xv = xs[m][k];
      ai = fmaf(xv, wi[k], ai);
      af = fmaf(xv, wf[k], af);
    }
    ai += __shfl_down(ai, 1); af += __shfl_down(af, 1);
    ai += __shfl_down(ai, 2); af += __shfl_down(af, 2);
    if (l4 == 0){
      int rowg = rt*16 + m;
      int t = rowg >> 3, b = rowg & 7;
      itb[(h*B_ + b)*T_ + t] = ai + bi[h];
      ftb[(h*B_ + b)*T_ + t] = af + bfv[h];
    }
  }
}

// ---------------- K3: per-head 5-matmul MFMA GEMM; frag-layout epilogues for attn ----------------
__global__ __launch_bounds__(256) void k_gemm5(
    const unsigned short* __restrict__ qkb, const unsigned short* __restrict__ xinb,
    const unsigned short* __restrict__ Wqt, const unsigned short* __restrict__ Wkt,
    const unsigned short* __restrict__ Wst, const unsigned short* __restrict__ Wvt,
    const unsigned short* __restrict__ Wot,
    const float* __restrict__ bq, const float* __restrict__ bk, const float* __restrict__ bsk,
    const float* __restrict__ bv, const float* __restrict__ bo,
    unsigned short* __restrict__ qob, unsigned short* __restrict__ kob,
    unsigned short* __restrict__ vot,
    float* __restrict__ hb, float* __restrict__ og){
  int bid = blockIdx.x;
  int rt  = bid & 15;
  int h   = (bid >> 4) & 3;
  int mat = bid >> 6;                    // 0=q 1=k 2=skip 3=v 4=og
  int tid = threadIdx.x;
  int w = tid >> 6, l = tid & 63;
  int lm = l & 15, lq = l >> 4;
  int r0 = rt * 32;
  const unsigned short* A = (mat < 3) ? (qkb + h*(TB_*D_)) : xinb;
  const unsigned short* Bt;
  const float* bias;
  switch (mat){
    case 0: Bt = Wqt; bias = bq;  break;
    case 1: Bt = Wkt; bias = bk;  break;
    case 2: Bt = Wst; bias = bsk; break;
    case 3: Bt = Wvt; bias = bv;  break;
    default: Bt = Wot; bias = bo; break;
  }
  Bt += h*(D_*D_);
  f32x4 acc[2][4];
  #pragma unroll
  for (int mt = 0; mt < 2; mt++)
    #pragma unroll
    for (int nt = 0; nt < 4; nt++) acc[mt][nt] = (f32x4){0.f,0.f,0.f,0.f};
  const unsigned short* Ap = A + l*8;
  const unsigned short* Bp = Bt + l*8;
  #pragma unroll
  for (int kc = 0; kc < 8; kc++){
    bf16x8 a0 = *(const bf16x8*)(Ap + ((rt*16      + kc) << 9));
    bf16x8 a1 = *(const bf16x8*)(Ap + ((rt*16 + 8  + kc) << 9));
    bf16x8 b0 = *(const bf16x8*)(Bp + (((w*4+0)*8 + kc) << 9));
    bf16x8 b1 = *(const bf16x8*)(Bp + (((w*4+1)*8 + kc) << 9));
    bf16x8 b2 = *(const bf16x8*)(Bp + (((w*4+2)*8 + kc) << 9));
    bf16x8 b3 = *(const bf16x8*)(Bp + (((w*4+3)*8 + kc) << 9));
    acc[0][0] = __builtin_amdgcn_mfma_f32_16x16x32_bf16(a0, b0, acc[0][0], 0, 0, 0);
    acc[0][1] = __builtin_amdgcn_mfma_f32_16x16x32_bf16(a0, b1, acc[0][1], 0, 0, 0);
    acc[0][2] = __builtin_amdgcn_mfma_f32_16x16x32_bf16(a0, b2, acc[0][2], 0, 0, 0);
    acc[0][3] = __builtin_amdgcn_mfma_f32_16x16x32_bf16(a0, b3, acc[0][3], 0, 0, 0);
    acc[1][0] = __builtin_amdgcn_mfma_f32_16x16x32_bf16(a1, b0, acc[1][0], 0, 0, 0);
    acc[1][1] = __builtin_amdgcn_mfma_f32_16x16x32_bf16(a1, b1, acc[1][1], 0, 0, 0);
    acc[1][2] = __builtin_amdgcn_mfma_f32_16x16x32_bf16(a1, b2, acc[1][2], 0, 0, 0);
    acc[1][3] = __builtin_amdgcn_mfma_f32_16x16x32_bf16(a1, b3, acc[1][3], 0, 0, 0);
  }
  float bval[4];
  #pragma unroll
  for (int nt = 0; nt < 4; nt++) bval[nt] = bias[h*D_ + w*64 + nt*16 + lm];
  #pragma unroll
  for (int mt = 0; mt < 2; mt++){
    #pragma unroll
    for (int r = 0; r < 4; r++){
      int row = r0 + mt*16 + lq*4 + r;
      int t = row >> 3, b = row & 7;
      #pragma unroll
      for (int nt = 0; nt < 4; nt++){
        int e = w*64 + nt*16 + lm;
        float vv = acc[mt][nt][r] + bval[nt];
        if (mat <= 1){
          if (mat == 1) vv *= 0.0625f;
          unsigned short* ob = (mat == 0) ? qob : kob;
          int mt2 = t >> 4, kb2 = e >> 5;
          int lane2 = ((e >> 3)&3)*16 + (t & 15);
          ob[(h*B_ + b)*16384 + ((mt2*8 + kb2)*64 + lane2)*8 + (e & 7)] = tobf_(vv);
        } else if (mat == 3){
          int nt3 = e >> 4, kb3 = t >> 5;
          int lane3 = ((t >> 3)&3)*16 + lm;
          vot[(h*B_ + b)*16384 + ((nt3*2 + kb3)*64 + lane3)*8 + (t & 7)] = tobf_(vv);
        } else {
          int obase = (((t*NH_ + h)*B_ + b) << 8) + e;
          if (mat == 4) og[obase] = sigm_(vv);
          else          hb[obase] = vv;        // skip term
        }
      }
    }
  }
}

// ---------------- K4: MFMA attention with fused gate scan ----------------
__global__ __launch_bounds__(256) void k_attn2(
    const unsigned short* __restrict__ qob, const unsigned short* __restrict__ kob,
    const unsigned short* __restrict__ vot, const float* __restrict__ og,
    const float* __restrict__ itb, const float* __restrict__ ftb,
    float* __restrict__ hb){
  __shared__ unsigned short Pf[1024];
  __shared__ float partial[4][16];
  __shared__ float scal[16];
  int bid = blockIdx.x;
  int hbx = bid >> 2, tq = bid & 3;
  int h = hbx >> 3, b = hbx & 7;
  int tid = threadIdx.x;
  int w = tid >> 6, l = tid & 63, lm = l & 15, lq = l >> 4;
  float F  = ftb[hbx*T_ + l];
  float it = itb[hbx*T_ + l];
  #pragma unroll
  for (int off = 1; off < 64; off <<= 1){
    float v2 = __shfl_up(F, off);
    if (l >= off) F += v2;
  }
  float ct = it - F;
  float G = ct;
  #pragma unroll
  for (int off = 1; off < 64; off <<= 1){
    float v2 = __shfl_up(G, off);
    if (l >= off) G = fmaxf(G, v2);
  }
  float rb = -fmaxf(0.f, G);
  const unsigned short* Aq = qob + hbx*16384 + l*8;
  const unsigned short* Bk = kob + hbx*16384 + l*8;
  f32x4 accs = (f32x4){0.f,0.f,0.f,0.f};
  #pragma unroll
  for (int kc = 0; kc < 8; kc++){
    bf16x8 a  = *(const bf16x8*)(Aq + ((tq*8 + kc) << 9));
    bf16x8 bb = *(const bf16x8*)(Bk + ((w*8  + kc) << 9));
    accs = __builtin_amdgcn_mfma_f32_16x16x32_bf16(a, bb, accs, 0, 0, 0);
  }
  int s = w*16 + lm;
  float ct_s = __shfl(ct, s);
  float p[4], ps[4];
  #pragma unroll
  for (int r = 0; r < 4; r++){
    int t = tq*16 + lq*4 + r;
    float rb_t = __shfl(rb, t);
    float pv = (s <= t) ? __expf(ct_s + rb_t) * accs[r] : 0.f;
    p[r] = pv; ps[r] = pv;
  }
  #pragma unroll
  for (int off = 1; off < 16; off <<= 1){
    #pragma unroll
    for (int r = 0; r < 4; r++) ps[r] += __shfl_xor(ps[r], off);
  }
  if (lm == 0){
    #pragma unroll
    for (int r = 0; r < 4; r++) partial[w][lq*4 + r] = ps[r];
  }
  {
    int kbP = w >> 1;
    int laneP = ((w*2 + (lm >> 3)) & 3)*16;
    int jP = lm & 7;
    #pragma unroll
    for (int r = 0; r < 4; r++){
      int m = lq*4 + r;
      Pf[(kbP*64 + laneP + m)*8 + jP] = tobf_(p[r]);
    }
  }
  __syncthreads();
  if (tid < 16){
    float sum = partial[0][tid] + partial[1][tid] + partial[2][tid] + partial[3][tid];
    scal[tid] = 1.0f / fmaxf(fabsf(sum), 1.0f);
  }
  bf16x8 pa0 = *(const bf16x8*)(Pf + l*8);
  bf16x8 pa1 = *(const bf16x8*)(Pf + 512 + l*8);
  const unsigned short* Bv = vot + hbx*16384 + l*8;
  f32x4 acco[4];
  #pragma unroll
  for (int nt = 0; nt < 4; nt++) acco[nt] = (f32x4){0.f,0.f,0.f,0.f};
  #pragma unroll
  for (int nt = 0; nt < 4; nt++){
    int nt3 = w*4 + nt;
    bf16x8 b0 = *(const bf16x8*)(Bv + ((nt3*2 + 0) << 9));
    bf16x8 b1 = *(const bf16x8*)(Bv + ((nt3*2 + 1) << 9));
    acco[nt] = __builtin_amdgcn_mfma_f32_16x16x32_bf16(pa0, b0, acco[nt], 0, 0, 0);
    acco[nt] = __builtin_amdgcn_mfma_f32_16x16x32_bf16(pa1, b1, acco[nt], 0, 0, 0);
  }
  __syncthreads();
  #pragma unroll
  for (int nt = 0; nt < 4; nt++){
    #pragma unroll
    for (int r = 0; r < 4; r++){
      int tl = lq*4 + r;
      int t = tq*16 + tl;
      int e = (w*4 + nt)*16 + lm;
      int idx = (((t*NH_ + h)*B_ + b) << 8) + e;
      hb[idx] += og[idx] * acco[nt][r] * scal[tl];
    }
  }
}

// ---------------- K5: fused bn2 (LDS-staged) + poll (K=1024, *trig) + down (K=256, +x) --------
// grid 32 (16 rows = 2 t per block), block 256 = 4 waves
__global__ __launch_bounds__(256) void k_tail4(
    const float* __restrict__ hbuf, const float* __restrict__ bn2s, const float* __restrict__ bn2b,
    const unsigned short* __restrict__ Wpt, const float* __restrict__ bp,
    const float* __restrict__ trig,
    const unsigned short* __restrict__ Wdt, const float* __restrict__ bd,
    const float* __restrict__ x, float* __restrict__ y){
  __shared__ __align__(16) float hs[2*32*D_];   // 64 KB: hbuf rows for t0,t1
  __shared__ unsigned short Af[16*1024];        // 32 KB: A-frag (M=16, K=1024); reused for zf
  int rt = blockIdx.x;                          // 0..31
  int tid = threadIdx.x;
  int w = tid >> 6, l = tid & 63, lm = l & 15, lq = l >> 4;
  // stage hbuf[t0..t1] coalesced
  const float* hp = hbuf + (rt*2)*(NH_*B_*D_);
  #pragma unroll
  for (int i = 0; i < 16; i++){
    int idx = (tid + i*256)*4;
    *(float4*)&hs[idx] = *(const float4*)&hp[idx];
  }
  __syncthreads();
  // bn2 stats per (t,d) column from LDS; write normalized values as A-frag (M=16, K=1024)
  #pragma unroll
  for (int p = 0; p < 2; p++){
    int c = tid + p*256;                 // 0..511 = tl*256 + d
    int tl = c >> 8, d = c & 255;
    const float* col = hs + tl*8192 + d;
    float v[32]; float mu = 0.f;
    #pragma unroll
    for (int i = 0; i < 32; i++){ v[i] = col[i*D_]; mu += v[i]; }
    mu *= (1.0f/32.0f);
    float var = 0.f;
    #pragma unroll
    for (int i = 0; i < 32; i++){ float dd = v[i]-mu; var += dd*dd; }
    var *= (1.0f/32.0f);
    float sc = (1.0f/sqrtf(var + EPS_)) * bn2s[d];
    float bs = bn2b[d];
    #pragma unroll
    for (int i = 0; i < 32; i++){        // i = h*8 + b
      int hh = i >> 3, b = i & 7;
      int m = tl*8 + b;                  // local row (m-tile 0 only)
      int k = hh*D_ + d;                 // K in [0,1024)
      Af[((k >> 5)*64 + ((k >> 3)&3)*16 + m)*8 + (k & 7)] = tobf_((v[i]-mu)*sc + bs);
    }
  }
  __syncthreads();
  // poll GEMM: M=16, N=256 (4 waves x 4 n-tiles), K=1024
  f32x4 acc[4];
  #pragma unroll
  for (int nt = 0; nt < 4; nt++) acc[nt] = (f32x4){0.f,0.f,0.f,0.f};
  const unsigned short* Bp = Wpt + l*8;
  #pragma unroll 4
  for (int kb = 0; kb < 32; kb++){
    bf16x8 a = *(const bf16x8*)(Af + (kb*64 + l)*8);
    #pragma unroll
    for (int nt = 0; nt < 4; nt++){
      bf16x8 bb = *(const bf16x8*)(Bp + (((w*4+nt)*32 + kb) << 9));
      acc[nt] = __builtin_amdgcn_mfma_f32_16x16x32_bf16(a, bb, acc[nt], 0, 0, 0);
    }
  }
  __syncthreads();                       // all Af reads done before reuse as zf
  unsigned short* zf = Af;               // z A-frag (M=16, K=256), 8 KB
  #pragma unroll
  for (int nt = 0; nt < 4; nt++){
    int e = w*64 + nt*16 + lm;
    float bpe = bp[e];
    #pragma unroll
    for (int r = 0; r < 4; r++){
      int ml = lq*4 + r;
      int row = rt*16 + ml;
      float z = (acc[nt][r] + bpe) * trig[row*D_ + e];
      zf[((e >> 5)*64 + ((e >> 3)&3)*16 + ml)*8 + (e & 7)] = tobf_(z);
    }
  }
  __syncthreads();
  // down GEMM: M=16, N=128 (4 waves x 2 n-tiles), K=256
  f32x4 acc2[2];
  acc2[0] = (f32x4){0.f,0.f,0.f,0.f};
  acc2[1] = (f32x4){0.f,0.f,0.f,0.f};
  const unsigned short* Bdp = Wdt + l*8;
  #pragma unroll
  for (int kc = 0; kc < 8; kc++){
    bf16x8 a = *(const bf16x8*)(zf + (kc*64 + l)*8);
    #pragma unroll
    for (int nt = 0; nt < 2; nt++){
      bf16x8 bb = *(const bf16x8*)(Bdp + (((w*2+nt)*8 + kc) << 9));
      acc2[nt] = __builtin_amdgcn_mfma_f32_16x16x32_bf16(a, bb, acc2[nt], 0, 0, 0);
    }
  }
  #pragma unroll
  for (int nt = 0; nt < 2; nt++){
    int hh = (w*2+nt)*16 + lm;
    float bde = bd[hh];
    #pragma unroll
    for (int r = 0; r < 4; r++){
      int row = rt*16 + lq*4 + r;
      y[row*H_ + hh] = acc2[nt][r] + bde + x[row*H_ + hh];
    }
  }
}

extern "C" void kernel_launch(void* const* d_in, const int* in_sizes, int n_in,
                              void* d_out, int out_size, void* d_ws, size_t ws_size,
                              hipStream_t stream){
  const float* x     = (const float*)d_in[0];
  const float* Wq    = (const float*)d_in[1];
  const float* bq    = (const float*)d_in[2];
  const float* Wk    = (const float*)d_in[3];
  const float* bk    = (const float*)d_in[4];
  const float* Wv    = (const float*)d_in[5];
  const float* bv    = (const float*)d_in[6];
  const float* ck    = (const float*)d_in[7];
  const float* cb    = (const float*)d_in[8];
  const float* Wi    = (const float*)d_in[9];
  const float* bi    = (const float*)d_in[10];
  const float* Wf    = (const float*)d_in[11];
  const float* bf    = (const float*)d_in[12];
  const float* Wo    = (const float*)d_in[13];
  const float* bo    = (const float*)d_in[14];
  const float* Wsk   = (const float*)d_in[15];
  const float* bsk   = (const float*)d_in[16];
  const float* bn1s  = (const float*)d_in[17];
  const float* bn1b  = (const float*)d_in[18];
  const float* bn2s  = (const float*)d_in[19];
  const float* bn2b  = (const float*)d_in[20];
  const float* Wup1  = (const float*)d_in[21];
  const float* bup1  = (const float*)d_in[22];
  const float* Wup2  = (const float*)d_in[23];
  const float* bup2  = (const float*)d_in[24];
  const float* Wp    = (const float*)d_in[25];
  const float* bp    = (const float*)d_in[26];
  const float* Wd    = (const float*)d_in[27];
  const float* bd    = (const float*)d_in[28];
  float* y = (float*)d_out;

  float* w = (float*)d_ws;
  float* trig = w;  w += T_*B_*D_;
  float* hbuf = w;  w += T_*NH_*B_*D_;
  float* og   = w;  w += T_*NH_*B_*D_;
  float* itb  = w;  w += NH_*B_*T_;
  float* ftb  = w;  w += NH_*B_*T_;
  unsigned short* xinb = (unsigned short*)w;  w += (T_*B_*D_)/2;
  unsigned short* qkb  = (unsigned short*)w;  w += (NH_*TB_*D_)/2;
  unsigned short* Wqt  = (unsigned short*)w;  w += (NH_*D_*D_)/2;
  unsigned short* Wkt  = (unsigned short*)w;  w += (NH_*D_*D_)/2;
  unsigned short* Wst  = (unsigned short*)w;  w += (NH_*D_*D_)/2;
  unsigned short* Wvt  = (unsigned short*)w;  w += (NH_*D_*D_)/2;
  unsigned short* Wot  = (unsigned short*)w;  w += (NH_*D_*D_)/2;
  unsigned short* Wu1t = (unsigned short*)w;  w += (H_*D_)/2;
  unsigned short* Wu2t = (unsigned short*)w;  w += (H_*D_)/2;
  unsigned short* qob  = (unsigned short*)w;  w += (NH_*B_*T_*D_)/2;
  unsigned short* kob  = (unsigned short*)w;  w += (NH_*B_*T_*D_)/2;
  unsigned short* vot  = (unsigned short*)w;  w += (NH_*B_*T_*D_)/2;
  unsigned short* Wpt  = (unsigned short*)w;  w += (NH_*D_*D_)/2;
  unsigned short* Wdt  = (unsigned short*)w;  w += (D_*H_)/2;

  k_prep <<<816, 256, 0, stream>>>(Wq, Wk, Wsk, Wv, Wo, Wup1, Wup2, Wp, Wd,
                                   Wqt, Wkt, Wst, Wvt, Wot, Wu1t, Wu2t, Wpt, Wdt);
  k_upcg <<<64, 256, 0, stream>>>(x, bn1s, bn1b, Wu1t, Wu2t, bup1, bup2, ck, cb,
                                  Wi, bi, Wf, bf, xinb, qkb, trig, itb, ftb);
  k_gemm5<<<320, 256, 0, stream>>>(qkb, xinb, Wqt, Wkt, Wst, Wvt, Wot,
                                   bq, bk, bsk, bv, bo, qob, kob, vot, hbuf, og);
  k_attn2<<<NH_*B_*4, 256, 0, stream>>>(qob, kob, vot, og, itb, ftb, hbuf);
  k_tail4<<<32, 256, 0, stream>>>(hbuf, bn2s, bn2b, Wpt, bp, trig, Wdt, bd, x, y);
}